// Round 1
// baseline (25.351 us; speedup 1.0000x reference)
//
#include <hip/hip_runtime.h>

#define NN 1024
#define DD 64
#define NF 11
#define TI 8
#define NEG_INF -1000000000.0f

__global__ __launch_bounds__(256) void featuresim_kernel(
    const float* __restrict__ x,
    const int* __restrict__ x_lengths,
    const float* __restrict__ fimp,
    float* __restrict__ out)
{
    const int tid = threadIdx.x;
    const int b   = blockIdx.x >> 7;            // 128 row-groups per batch
    const int i0  = (blockIdx.x & 127) * TI;
    const int len = x_lengths[b];

    // feature_importance: uniform address -> s_load, lives in SGPRs
    float fi[NF];
    #pragma unroll
    for (int k = 0; k < NF; ++k) fi[k] = fimp[k];

    // each thread owns 4 consecutive j's; hold their 11 features in VGPRs,
    // reused across all TI rows (no LDS on the hot path)
    const int j0 = tid * 4;
    float fj[4][NF];
    #pragma unroll
    for (int jj = 0; jj < 4; ++jj) {
        const float4* p = reinterpret_cast<const float4*>(
            x + (size_t)(b * NN + j0 + jj) * DD);
        float4 a = p[0], c = p[1], d = p[2];
        fj[jj][0] = a.x; fj[jj][1] = a.y; fj[jj][2]  = a.z; fj[jj][3] = a.w;
        fj[jj][4] = c.x; fj[jj][5] = c.y; fj[jj][6]  = c.z; fj[jj][7] = c.w;
        fj[jj][8] = d.x; fj[jj][9] = d.y; fj[jj][10] = d.z;
    }

    const int lane = tid & 63;
    const int wid  = tid >> 6;
    __shared__ float red_max[4];
    __shared__ float red_sum[4];

    for (int r = 0; r < TI; ++r) {
        const int i = i0 + r;
        // query row: wave-uniform address -> scalar loads
        const float* qp = x + (size_t)(b * NN + i) * DD;
        float q[NF];
        #pragma unroll
        for (int k = 0; k < NF; ++k) q[k] = qp[k];

        float v[4];
        #pragma unroll
        for (int jj = 0; jj < 4; ++jj) {
            float s = 0.0f;
            #pragma unroll
            for (int k = 0; k < NF; ++k)
                s = fmaf(fabsf(q[k] - fj[jj][k]), fi[k], s);
            float val = (s < 1.0f) ? -s : 0.0f;   // -attn * (attn < 1)
            v[jj] = ((j0 + jj) < len) ? val : NEG_INF;
        }

        // row max: 4-local -> wave shuffle -> cross-wave via LDS
        float m = fmaxf(fmaxf(v[0], v[1]), fmaxf(v[2], v[3]));
        #pragma unroll
        for (int off = 32; off >= 1; off >>= 1)
            m = fmaxf(m, __shfl_xor(m, off, 64));
        if (lane == 0) red_max[wid] = m;
        __syncthreads();
        m = fmaxf(fmaxf(red_max[0], red_max[1]),
                  fmaxf(red_max[2], red_max[3]));

        float e[4];
        float s = 0.0f;
        #pragma unroll
        for (int jj = 0; jj < 4; ++jj) {
            e[jj] = __expf(v[jj] - m);
            s += e[jj];
        }
        #pragma unroll
        for (int off = 32; off >= 1; off >>= 1)
            s += __shfl_xor(s, off, 64);
        if (lane == 0) red_sum[wid] = s;
        __syncthreads();
        s = red_sum[0] + red_sum[1] + red_sum[2] + red_sum[3];

        const float inv = 1.0f / s;
        float4 o = make_float4(e[0] * inv, e[1] * inv, e[2] * inv, e[3] * inv);
        reinterpret_cast<float4*>(out + (size_t)(b * NN + i) * NN + j0)[0] = o;
        // no third barrier needed: red_max writes for row r+1 happen after
        // barrier2 (above), red_max reads for row r happened before it;
        // red_sum writes for r+1 happen after barrier1 of r+1.
    }
}

extern "C" void kernel_launch(void* const* d_in, const int* in_sizes, int n_in,
                              void* d_out, int out_size, void* d_ws, size_t ws_size,
                              hipStream_t stream) {
    const float* x    = (const float*)d_in[0];
    const int*   xlen = (const int*)d_in[1];
    const float* fimp = (const float*)d_in[2];
    float*       out  = (float*)d_out;

    const int B = in_sizes[1];                  // 8
    dim3 grid(B * (NN / TI));                   // 1024 blocks
    dim3 block(256);
    featuresim_kernel<<<grid, block, 0, stream>>>(x, xlen, fimp, out);
}

// Round 2
// 23.212 us; speedup vs baseline: 1.0922x; 1.0922x over previous
//
#include <hip/hip_runtime.h>

#define NN 1024
#define DD 64
#define NF 11
#define TI 8

// Softmax-without-max is exact here: valid scores are in (-1, ~few] and
// masked scores are -1e9 -> __expf underflows to +0.0 exactly. len >= 1
// guarantees every row-sum > 0 (no NaN path).
__global__ __launch_bounds__(256, 4) void featuresim_kernel(
    const float* __restrict__ x,
    const int* __restrict__ x_lengths,
    const float* __restrict__ fimp,
    float* __restrict__ out)
{
    const int tid = threadIdx.x;
    const int b   = blockIdx.x >> 7;            // 128 row-groups per batch
    const int i0  = (blockIdx.x & 127) * TI;
    const int len = x_lengths[b];

    // feature_importance: uniform address -> s_load -> SGPRs
    float fi[NF];
    #pragma unroll
    for (int k = 0; k < NF; ++k) fi[k] = fimp[k];

    // each thread owns 4 consecutive j's; their 11 features live in VGPRs
    // for the whole kernel (reused across all TI rows)
    const int j0 = tid * 4;
    float fj[4][NF];
    #pragma unroll
    for (int jj = 0; jj < 4; ++jj) {
        const float4* p = reinterpret_cast<const float4*>(
            x + (size_t)(b * NN + j0 + jj) * DD);
        float4 a = p[0], c = p[1], d = p[2];
        fj[jj][0] = a.x; fj[jj][1] = a.y; fj[jj][2]  = a.z; fj[jj][3] = a.w;
        fj[jj][4] = c.x; fj[jj][5] = c.y; fj[jj][6]  = c.z; fj[jj][7] = c.w;
        fj[jj][8] = d.x; fj[jj][9] = d.y; fj[jj][10] = d.z;
    }

    __shared__ float partials[TI][256];   // [row][thread] — conflict-free both phases
    __shared__ float totals[TI];

    float e[TI][4];                       // statically indexed (full unroll) -> stays in VGPRs

    // ---- phase 1: all 8 rows' exp values + per-thread partial sums, NO barriers
    #pragma unroll
    for (int r = 0; r < TI; ++r) {
        const float* qp = x + (size_t)(b * NN + i0 + r) * DD;  // uniform -> s_load
        float q[NF];
        #pragma unroll
        for (int k = 0; k < NF; ++k) q[k] = qp[k];

        float sum4 = 0.0f;
        #pragma unroll
        for (int jj = 0; jj < 4; ++jj) {
            float s = 0.0f;
            #pragma unroll
            for (int k = 0; k < NF; ++k)
                s = fmaf(fabsf(q[k] - fj[jj][k]), fi[k], s);
            float val = (s < 1.0f) ? -s : 0.0f;            // -attn * (attn < 1)
            float ev  = ((j0 + jj) < len) ? __expf(val) : 0.0f;
            e[r][jj] = ev;
            sum4 += ev;
        }
        partials[r][tid] = sum4;
    }
    __syncthreads();

    // ---- phase 2: wave w reduces rows 2w, 2w+1 (chains pipelined)
    const int lane = tid & 63;
    const int wid  = tid >> 6;
    #pragma unroll
    for (int h = 0; h < 2; ++h) {
        const int r = wid * 2 + h;
        float s = partials[r][lane]       + partials[r][lane + 64]
                + partials[r][lane + 128] + partials[r][lane + 192];
        #pragma unroll
        for (int off = 32; off >= 1; off >>= 1)
            s += __shfl_xor(s, off, 64);
        if (lane == 0) totals[r] = s;
    }
    __syncthreads();

    // ---- phase 3: normalize + coalesced float4 stores
    #pragma unroll
    for (int r = 0; r < TI; ++r) {
        const float inv = __builtin_amdgcn_rcpf(totals[r]);   // broadcast read
        float4 o = make_float4(e[r][0] * inv, e[r][1] * inv,
                               e[r][2] * inv, e[r][3] * inv);
        reinterpret_cast<float4*>(
            out + (size_t)(b * NN + i0 + r) * NN + j0)[0] = o;
    }
}

extern "C" void kernel_launch(void* const* d_in, const int* in_sizes, int n_in,
                              void* d_out, int out_size, void* d_ws, size_t ws_size,
                              hipStream_t stream) {
    const float* x    = (const float*)d_in[0];
    const int*   xlen = (const int*)d_in[1];
    const float* fimp = (const float*)d_in[2];
    float*       out  = (float*)d_out;

    const int B = in_sizes[1];                  // 8
    dim3 grid(B * (NN / TI));                   // 1024 blocks
    dim3 block(256);
    featuresim_kernel<<<grid, block, 0, stream>>>(x, xlen, fimp, out);
}